// Round 1
// baseline (88.970 us; speedup 1.0000x reference)
//
#include <hip/hip_runtime.h>
#include <math.h>

#define NQ 192

__global__ __launch_bounds__(256) void matern_tile_kernel(
    const float* __restrict__ X,        // [N][32]
    const float* __restrict__ nu_p,
    const float* __restrict__ logvar_p,
    const float* __restrict__ logls_p,
    float* __restrict__ out, int N)
{
    __shared__ float sXi[32][33];
    __shared__ float sXj[32][33];
    __shared__ __align__(16) float2 sCoef[NQ];   // (cosh t_q, w_q * cosh(nu t_q))
    __shared__ float sScal[3];                   // scale, norm, var

    const int t  = threadIdx.x;
    const int i0 = blockIdx.y * 32;
    const int j0 = blockIdx.x * 32;

    // ---- stage X tiles into LDS (coalesced) ----
    #pragma unroll
    for (int u = 0; u < 4; ++u) {
        int f = t + u * 256;
        int r = f >> 5, d = f & 31;
        sXi[r][d] = X[(i0 + r) * 32 + d];
        sXj[r][d] = X[(j0 + r) * 32 + d];
    }

    const float nu = nu_p[0];

    // ---- quadrature coefficients (once per block) ----
    if (t < NQ) {
        const float h = 6.0f / 191.0f;
        float tq = h * (float)t;
        float w  = (t == 0 || t == NQ - 1) ? 0.5f * h : h;
        sCoef[t] = make_float2(coshf(tq), w * coshf(nu * tq));
    }
    if (t == 0) {
        float var = expf(logvar_p[0]);
        float ls  = expf(logls_p[0]);
        sScal[0] = sqrtf(2.0f * nu) / ls;                              // sqrt(2nu)/l
        sScal[1] = var * expf((1.0f - nu) * 0.69314718056f - lgammaf(nu)); // var*2^(1-nu)/Gamma(nu)
        sScal[2] = var;
    }
    __syncthreads();

    const float scale = sScal[0];
    const float norm  = sScal[1];
    const float var   = sScal[2];

    const int jl = t & 31;          // output column within tile (coalesced lanes)
    const int ig = (t >> 5) * 4;    // base output row within tile; thread owns 4 rows

    // ---- pairwise squared distances (direct diff-square; LDS broadcast on i, conflict-free on j) ----
    float d2[4] = {0.f, 0.f, 0.f, 0.f};
    #pragma unroll 8
    for (int d = 0; d < 32; ++d) {
        float xj = sXj[jl][d];
        #pragma unroll
        for (int k = 0; k < 4; ++k) {
            float df = sXi[ig + k][d] - xj;
            d2[k] = fmaf(df, df, d2[k]);
        }
    }

    float x[4], acc[4];
    #pragma unroll
    for (int k = 0; k < 4; ++k) {
        float dist = sqrtf(fmaxf(d2[k], 1e-24f));
        x[k]  = fmaxf(scale * dist, 1e-10f);
        acc[k] = 0.f;
    }

    // ---- 192-point trapezoid quadrature: sum_q coef_q * exp(-x * cosh(t_q)) ----
    // (exp(-x) folded into the exponent)
    for (int q = 0; q < NQ; q += 2) {
        float4 cc = *reinterpret_cast<const float4*>(&sCoef[q]);
        #pragma unroll
        for (int k = 0; k < 4; ++k)
            acc[k] = fmaf(cc.y, __expf(-x[k] * cc.x), acc[k]);
        #pragma unroll
        for (int k = 0; k < 4; ++k)
            acc[k] = fmaf(cc.w, __expf(-x[k] * cc.z), acc[k]);
    }

    // ---- k = norm * x^nu * K-sum; diagonal = var ----
    #pragma unroll
    for (int k = 0; k < 4; ++k) {
        float pw  = __expf(nu * __logf(x[k]));
        float val = norm * pw * acc[k];
        int gi = i0 + ig + k, gj = j0 + jl;
        out[gi * N + gj] = (gi == gj) ? var : val;
    }
}

extern "C" void kernel_launch(void* const* d_in, const int* in_sizes, int n_in,
                              void* d_out, int out_size, void* d_ws, size_t ws_size,
                              hipStream_t stream) {
    const float* X  = (const float*)d_in[0];
    const float* nu = (const float*)d_in[1];
    const float* lv = (const float*)d_in[2];
    const float* ll = (const float*)d_in[3];
    float* out = (float*)d_out;

    const int N = in_sizes[0] / 32;        // 1024
    dim3 grid(N / 32, N / 32);
    matern_tile_kernel<<<grid, 256, 0, stream>>>(X, nu, lv, ll, out, N);
}

// Round 2
// 75.044 us; speedup vs baseline: 1.1856x; 1.1856x over previous
//
#include <hip/hip_runtime.h>
#include <math.h>

#define NQ 192
#define TMAX 6.0f
#define LOG2E 1.44269504088896340736f
#define LN2   0.69314718055994530942f

// ---- one tiny block: quadrature table + derived scalars into d_ws ----
__global__ __launch_bounds__(192) void matern_coef_kernel(
    const float* __restrict__ nu_p, const float* __restrict__ lv_p,
    const float* __restrict__ ll_p, float2* __restrict__ coef,
    float* __restrict__ scal)
{
    const int t = threadIdx.x;
    const float nu = nu_p[0];
    const float h = TMAX / (float)(NQ - 1);
    const float tq = h * (float)t;
    const float w  = (t == 0 || t == NQ - 1) ? 0.5f * h : h;
    const float cosh_t  = 0.5f * (__expf(tq) + __expf(-tq));
    const float cosh_nt = 0.5f * (__expf(nu * tq) + __expf(-nu * tq));
    coef[t] = make_float2(cosh_t * LOG2E, w * cosh_nt);   // (cosh(t)*log2e, w*cosh(nu t))
    if (t == 0) {
        const float var = __expf(lv_p[0]);
        const float ls  = __expf(ll_p[0]);
        scal[0] = sqrtf(2.0f * nu) / ls;                          // scale
        scal[1] = var * __expf((1.0f - nu) * LN2 - lgammaf(nu));  // var*2^(1-nu)/Gamma(nu)
        scal[2] = var;
        scal[3] = nu;
    }
}

// ---- upper-triangle 16x16 tiles, 1 wave per block, mirror-write transposed tile ----
__global__ __launch_bounds__(64) void matern_tri_kernel(
    const float* __restrict__ X,
    const float4* __restrict__ coef4,
    const float* __restrict__ scal,
    float* __restrict__ out, int N)
{
    __shared__ float sXi[16][36];     // padded: float4-aligned rows, 2-way-max bank alias
    __shared__ float sXj[16][36];
    __shared__ float sT[16][17];
    __shared__ float4 sC4[NQ / 2];

    const int lane = threadIdx.x;
    const int nt = N >> 4;

    // decode linear block id -> (by, bx) with bx >= by
    int rem = (int)blockIdx.x, by = 0;
    while (rem >= nt - by) { rem -= nt - by; ++by; }
    const int bx = by + rem;
    const int i0 = by << 4, j0 = bx << 4;

    // stage X tiles (float4, coalesced)
    #pragma unroll
    for (int u = 0; u < 2; ++u) {
        int f = lane + (u << 6);            // float4 slot 0..127
        int r = f >> 3, c4 = (f & 7) << 2;
        *(float4*)&sXi[r][c4] = *(const float4*)&X[(i0 + r) * 32 + c4];
        *(float4*)&sXj[r][c4] = *(const float4*)&X[(j0 + r) * 32 + c4];
    }
    // stage quadrature coefficients (1.5 KB)
    for (int u = lane; u < NQ / 2; u += 64) sC4[u] = coef4[u];
    __syncthreads();

    const float scale = scal[0], norm = scal[1], var = scal[2], nu = scal[3];

    const int jl = lane & 15;           // column within tile
    const int i4 = (lane >> 4) << 2;    // 4 rows per thread

    // pairwise squared distances
    float d2[4] = {0.f, 0.f, 0.f, 0.f};
    #pragma unroll
    for (int d = 0; d < 32; ++d) {
        const float xj = sXj[jl][d];
        #pragma unroll
        for (int k = 0; k < 4; ++k) {
            const float df = sXi[i4 + k][d] - xj;
            d2[k] = fmaf(df, df, d2[k]);
        }
    }

    float x[4], xn[4], acc[4];
    #pragma unroll
    for (int k = 0; k < 4; ++k) {
        const float dist = sqrtf(fmaxf(d2[k], 1e-24f));
        x[k]  = fmaxf(scale * dist, 1e-10f);
        xn[k] = -x[k];
        acc[k] = 0.f;
    }

    // wave-uniform trip count: beyond qp every exp2 arg < -150 -> exactly 0 in f32
    float xmin = fminf(fminf(x[0], x[1]), fminf(x[2], x[3]));
    #pragma unroll
    for (int o = 32; o > 0; o >>= 1) xmin = fminf(xmin, __shfl_xor(xmin, o));
    const float cosh_cut = 150.0f / (LOG2E * xmin);
    int qp = NQ / 2;
    if (cosh_cut < 205.0f) {            // cosh(TMAX) ~ 201.7
        const float y = cosh_cut + sqrtf(fmaxf(cosh_cut * cosh_cut - 1.0f, 0.0f));
        const float tcut = LN2 * __builtin_amdgcn_logf(fmaxf(y, 1.0f));   // acosh
        const float h = TMAX / (float)(NQ - 1);
        const int idx = (int)(tcut / h) + 1;
        qp = min(NQ / 2, (idx >> 1) + 1);
    }
    qp = __builtin_amdgcn_readfirstlane(qp);

    // 2 quadrature points per iteration: 8 exp2 + 8 mul + 8 fma per thread
    #pragma unroll 2
    for (int q = 0; q < qp; ++q) {
        const float4 cc = sC4[q];
        #pragma unroll
        for (int k = 0; k < 4; ++k)
            acc[k] = fmaf(cc.y, __builtin_amdgcn_exp2f(xn[k] * cc.x), acc[k]);
        #pragma unroll
        for (int k = 0; k < 4; ++k)
            acc[k] = fmaf(cc.w, __builtin_amdgcn_exp2f(xn[k] * cc.z), acc[k]);
    }

    // epilogue: k = norm * x^nu * sum ; diagonal = var ; stage for mirror
    #pragma unroll
    for (int k = 0; k < 4; ++k) {
        const float pw = __builtin_amdgcn_exp2f(nu * __builtin_amdgcn_logf(x[k]));
        float val = norm * pw * acc[k];
        const int gi = i0 + i4 + k, gj = j0 + jl;
        if (gi == gj) val = var;
        out[gi * N + gj] = val;
        sT[i4 + k][jl] = val;
    }
    if (bx != by) {
        __syncthreads();
        #pragma unroll
        for (int k = 0; k < 4; ++k) {
            const int a = i4 + k;                       // transposed-tile row
            out[(j0 + a) * N + (i0 + jl)] = sT[jl][a];  // coalesced, conflict-free-ish
        }
    }
}

extern "C" void kernel_launch(void* const* d_in, const int* in_sizes, int n_in,
                              void* d_out, int out_size, void* d_ws, size_t ws_size,
                              hipStream_t stream) {
    const float* X  = (const float*)d_in[0];
    const float* nu = (const float*)d_in[1];
    const float* lv = (const float*)d_in[2];
    const float* ll = (const float*)d_in[3];
    float* out = (float*)d_out;

    const int N = in_sizes[0] / 32;        // 1024
    float2* coef = (float2*)d_ws;
    float*  scal = (float*)d_ws + 2 * NQ;

    matern_coef_kernel<<<1, NQ, 0, stream>>>(nu, lv, ll, coef, scal);

    const int nt = N / 16;
    const int nblk = nt * (nt + 1) / 2;    // 2080 for N=1024
    matern_tri_kernel<<<nblk, 64, 0, stream>>>(X, (const float4*)coef, scal, out, N);
}

// Round 3
// 67.629 us; speedup vs baseline: 1.3156x; 1.1096x over previous
//
#include <hip/hip_runtime.h>
#include <math.h>

#define NQ 192
#define TMAX 6.0f
#define LOG2E 1.44269504088896340736f
#define LN2   0.69314718055994530942f
#define HSTEP (6.0f / 191.0f)
#define INVH  (191.0f / 6.0f)

__device__ __forceinline__ float fast_ln(float v) {
    return LN2 * __builtin_amdgcn_logf(v);   // v_log_f32 is log2
}

// upper-triangle 16x16 tiles, 128 threads (2 waves), 2 rows/thread, mirror write
__global__ __launch_bounds__(128) void matern_tri_kernel(
    const float* __restrict__ X,
    const float* __restrict__ nu_p, const float* __restrict__ lv_p,
    const float* __restrict__ ll_p,
    float* __restrict__ out, int N)
{
    __shared__ float sXi[16][36];
    __shared__ float sXj[16][36];
    __shared__ float sT[16][17];
    __shared__ __align__(16) float4 sC4[NQ / 2];
    __shared__ float sScal[4];

    const int t  = threadIdx.x;
    const int nt = N >> 4;
    const int tot = 2 * nt + 1;                   // 129

    // ---- closed-form triangular decode (sqrt estimate + robust fixup) ----
    const int B = (int)blockIdx.x;
    int by = (int)(((float)tot - sqrtf((float)(tot * tot - 8 * B))) * 0.5f);
    if (by < 0) by = 0;
    while (by * (tot - by) / 2 > B) --by;
    while ((by + 1) * (tot - by - 1) / 2 <= B) ++by;
    const int bx = by + (B - by * (tot - by) / 2);
    const int i0 = by << 4, j0 = bx << 4;

    // ---- stage X tiles: one float4 per thread per tile ----
    {
        const int r = t >> 3, c4 = (t & 7) << 2;
        *(float4*)&sXi[r][c4] = *(const float4*)&X[(i0 + r) * 32 + c4];
        *(float4*)&sXj[r][c4] = *(const float4*)&X[(j0 + r) * 32 + c4];
    }

    const float nu = nu_p[0];

    // ---- quadrature table inline: threads 0..95 compute 2 points each ----
    if (t < 96) {
        const float tq0 = HSTEP * (float)(2 * t);
        const float tq1 = HSTEP * (float)(2 * t + 1);
        const float w0 = (t == 0)  ? 0.5f * HSTEP : HSTEP;
        const float w1 = (t == 95) ? 0.5f * HSTEP : HSTEP;
        const float ch0 = 0.5f * (__expf(tq0) + __expf(-tq0));
        const float ch1 = 0.5f * (__expf(tq1) + __expf(-tq1));
        const float cn0 = 0.5f * (__expf(nu * tq0) + __expf(-nu * tq0));
        const float cn1 = 0.5f * (__expf(nu * tq1) + __expf(-nu * tq1));
        sC4[t] = make_float4(ch0 * LOG2E, w0 * cn0, ch1 * LOG2E, w1 * cn1);
    }
    if (t == 127) {
        const float var = __expf(lv_p[0]);
        const float ls  = __expf(ll_p[0]);
        const float lnorm = fast_ln(var) + (1.0f - nu) * LN2 - lgammaf(nu);
        sScal[0] = sqrtf(2.0f * nu) / ls;                 // scale
        sScal[1] = __expf(lnorm);                          // norm
        sScal[2] = var;
        sScal[3] = lnorm + fast_ln(HSTEP) + 12.72f;        // Cbase = ln(norm*h) - ln(3e-6)
    }
    __syncthreads();

    const float scale = sScal[0], norm = sScal[1], var = sScal[2], Cbase = sScal[3];

    const int jl = t & 15;             // tile column
    const int i2 = (t >> 4) << 1;      // rows i2, i2+1

    // ---- pairwise squared distances ----
    float d2[2] = {0.f, 0.f};
    #pragma unroll
    for (int d = 0; d < 32; ++d) {
        const float xj = sXj[jl][d];
        #pragma unroll
        for (int k = 0; k < 2; ++k) {
            const float df = sXi[i2 + k][d] - xj;
            d2[k] = fmaf(df, df, d2[k]);
        }
    }

    float x[2], xn[2], acc[2];
    bool isdiag[2];
    #pragma unroll
    for (int k = 0; k < 2; ++k) {
        const float dist = sqrtf(fmaxf(d2[k], 1e-24f));
        x[k]  = fmaxf(scale * dist, 1e-10f);
        xn[k] = -x[k];
        acc[k] = 0.f;
        isdiag[k] = (i0 + i2 + k) == (j0 + jl);
    }

    // ---- contribution-based trip count ----
    // cut at smallest t >= asinh(nu/x) with x*cosh(t) - nu*t > C,
    // where C = ln(norm * x^nu * h) - ln(tol); beyond it every term adds < tol to val.
    const float xe = fminf(isdiag[0] ? 1e30f : x[0], isdiag[1] ? 1e30f : x[1]);
    const float C  = Cbase + nu * fast_ln(xe);
    const float rr = nu / xe;
    float tc = fast_ln(rr + sqrtf(fmaf(rr, rr, 1.0f)));   // asinh: integrand peak
    #pragma unroll
    for (int it = 0; it < 4; ++it) {
        const float c = (C + nu * tc) / xe;
        tc = (c > 1.0f) ? fast_ln(c + sqrtf(fmaf(c, c, -1.0f))) : 0.0f;  // acosh
    }
    tc = fminf(tc, TMAX);
    int qp = min(NQ / 2, (int)(tc * INVH) / 2 + 3);       // pair index + margin
    #pragma unroll
    for (int o = 32; o > 0; o >>= 1) qp = max(qp, __shfl_xor(qp, o));
    qp = __builtin_amdgcn_readfirstlane(qp);

    // ---- quadrature: 2 points x 2 elems per iter (4 independent exp chains) ----
    #pragma unroll 2
    for (int q = 0; q < qp; ++q) {
        const float4 cc = sC4[q];
        acc[0] = fmaf(cc.y, __builtin_amdgcn_exp2f(xn[0] * cc.x), acc[0]);
        acc[1] = fmaf(cc.y, __builtin_amdgcn_exp2f(xn[1] * cc.x), acc[1]);
        acc[0] = fmaf(cc.w, __builtin_amdgcn_exp2f(xn[0] * cc.z), acc[0]);
        acc[1] = fmaf(cc.w, __builtin_amdgcn_exp2f(xn[1] * cc.z), acc[1]);
    }

    // ---- epilogue: val = norm * x^nu * acc ; diagonal = var ; mirror via LDS ----
    #pragma unroll
    for (int k = 0; k < 2; ++k) {
        const float pw = __builtin_amdgcn_exp2f(nu * __builtin_amdgcn_logf(x[k]));
        float val = norm * pw * acc[k];
        if (isdiag[k]) val = var;
        out[(i0 + i2 + k) * N + (j0 + jl)] = val;
        sT[i2 + k][jl] = val;
    }
    if (bx != by) {
        __syncthreads();
        #pragma unroll
        for (int k = 0; k < 2; ++k) {
            const int a = i2 + k;
            out[(j0 + a) * N + (i0 + jl)] = sT[jl][a];
        }
    }
}

extern "C" void kernel_launch(void* const* d_in, const int* in_sizes, int n_in,
                              void* d_out, int out_size, void* d_ws, size_t ws_size,
                              hipStream_t stream) {
    const float* X  = (const float*)d_in[0];
    const float* nu = (const float*)d_in[1];
    const float* lv = (const float*)d_in[2];
    const float* ll = (const float*)d_in[3];
    float* out = (float*)d_out;

    const int N  = in_sizes[0] / 32;              // 1024
    const int nt = N / 16;
    const int nblk = nt * (nt + 1) / 2;           // 2080
    matern_tri_kernel<<<nblk, 128, 0, stream>>>(X, nu, lv, ll, out, N);
}

// Round 4
// 66.472 us; speedup vs baseline: 1.3385x; 1.0174x over previous
//
#include <hip/hip_runtime.h>
#include <math.h>

#define NQ 192
#define NP 96                 // full-res float4 pairs (2 points each)
#define NP4 24                // stride-4 float4 pairs (points 8u, 8u+4; w=4h)
#define TMAX 6.0f
#define LOG2E 1.44269504088896340736f
#define LN2   0.69314718055994530942f
#define HSTEP (6.0f / 191.0f)
#define INVH  (191.0f / 6.0f)

__device__ __forceinline__ float fast_ln(float v) {
    return LN2 * __builtin_amdgcn_logf(v);      // v_log_f32 is log2
}
__device__ __forceinline__ float coshq(float a) {
    return 0.5f * (__expf(a) + __expf(-a));
}

// upper-triangle 16x16 tiles, 128 threads (2 waves), 2 rows/thread, mirror write
__global__ __launch_bounds__(128) void matern_tri_kernel(
    const float* __restrict__ X,
    const float* __restrict__ nu_p, const float* __restrict__ lv_p,
    const float* __restrict__ ll_p,
    float* __restrict__ out, int N)
{
    __shared__ float sXi[16][36];
    __shared__ float sXj[16][36];
    __shared__ float sT[16][17];
    __shared__ __align__(16) float4 sC[NP + NP4];
    __shared__ float sScal[4];

    const int t  = threadIdx.x;
    const int nt = N >> 4;
    const int tot = 2 * nt + 1;

    // ---- closed-form triangular decode ----
    const int B = (int)blockIdx.x;
    int by = (int)(((float)tot - sqrtf((float)(tot * tot - 8 * B))) * 0.5f);
    if (by < 0) by = 0;
    while (by * (tot - by) / 2 > B) --by;
    while ((by + 1) * (tot - by - 1) / 2 <= B) ++by;
    const int bx = by + (B - by * (tot - by) / 2);
    const int i0 = by << 4, j0 = bx << 4;

    // ---- stage X tiles ----
    {
        const int r = t >> 3, c4 = (t & 7) << 2;
        *(float4*)&sXi[r][c4] = *(const float4*)&X[(i0 + r) * 32 + c4];
        *(float4*)&sXj[r][c4] = *(const float4*)&X[(j0 + r) * 32 + c4];
    }

    const float nu = nu_p[0];

    // ---- quadrature tables inline ----
    if (t < NP) {                       // full-res: points 2t, 2t+1
        const float tq0 = HSTEP * (float)(2 * t);
        const float tq1 = HSTEP * (float)(2 * t + 1);
        const float w0 = (t == 0)      ? 0.5f * HSTEP : HSTEP;
        const float w1 = (t == NP - 1) ? 0.5f * HSTEP : HSTEP;
        sC[t] = make_float4(coshq(tq0) * LOG2E, w0 * coshq(nu * tq0),
                            coshq(tq1) * LOG2E, w1 * coshq(nu * tq1));
    } else if (t < NP + NP4) {          // stride-4: points 8u, 8u+4
        const int u = t - NP;
        const float tq0 = HSTEP * (float)(8 * u);
        const float tq1 = HSTEP * (float)(8 * u + 4);
        const float w0 = (u == 0)       ? 2.0f * HSTEP : 4.0f * HSTEP;
        const float w1 = (u == NP4 - 1) ? 2.0f * HSTEP : 4.0f * HSTEP;
        sC[t] = make_float4(coshq(tq0) * LOG2E, w0 * coshq(nu * tq0),
                            coshq(tq1) * LOG2E, w1 * coshq(nu * tq1));
    }
    if (t == 127) {
        const float var = __expf(lv_p[0]);
        const float ls  = __expf(ll_p[0]);
        const float lnorm = fast_ln(var) + (1.0f - nu) * LN2 - lgammaf(nu);
        sScal[0] = sqrtf(2.0f * nu) / ls;                  // scale
        sScal[1] = __expf(lnorm);                          // norm
        sScal[2] = var;
        // Cbase = ln(norm * 4h / tol), tol = 3e-4 (term-contribution threshold)
        sScal[3] = lnorm + fast_ln(4.0f * HSTEP) + 8.112f;
    }
    __syncthreads();

    const float scale = sScal[0], norm = sScal[1], var = sScal[2], Cbase = sScal[3];

    const int jl = t & 15;
    const int i2 = (t >> 4) << 1;

    // ---- pairwise squared distances ----
    float d2[2] = {0.f, 0.f};
    #pragma unroll
    for (int d = 0; d < 32; ++d) {
        const float xj = sXj[jl][d];
        #pragma unroll
        for (int k = 0; k < 2; ++k) {
            const float df = sXi[i2 + k][d] - xj;
            d2[k] = fmaf(df, df, d2[k]);
        }
    }

    float x[2], xn[2], acc[2];
    bool isdiag[2];
    #pragma unroll
    for (int k = 0; k < 2; ++k) {
        const float dist = sqrtf(fmaxf(d2[k], 1e-24f));
        x[k]  = fmaxf(scale * dist, 1e-10f);
        xn[k] = -x[k];
        acc[k] = 0.f;
        isdiag[k] = (i0 + i2 + k) == (j0 + jl);
    }

    // ---- wave-min x (diagonal excluded; window is widest at x_min) ----
    float xm = fminf(isdiag[0] ? 1e30f : x[0], isdiag[1] ? 1e30f : x[1]);
    #pragma unroll
    for (int o = 32; o > 0; o >>= 1) xm = fminf(xm, __shfl_xor(xm, o));

    // ---- significant-term window: { t : x*cosh(t) - nu*t < C } ----
    const float C = Cbase + nu * fast_ln(xm);
    // right edge: acosh fixed point from the integrand peak (converges from below)
    const float rr = nu / xm;
    float th = fast_ln(rr + sqrtf(fmaf(rr, rr, 1.0f)));    // asinh(nu/x) = peak
    #pragma unroll
    for (int it = 0; it < 6; ++it) {
        const float c = (C + nu * th) / xm;
        th = (c > 1.0f) ? fast_ln(c + sqrtf(fmaf(c, c, -1.0f))) : 0.0f;
    }
    th = fminf(th, TMAX);
    // left edge: t <- (x*cosh(t) - C)/nu from 0 (converges from below -> safe)
    float tl = fmaxf((xm - C) / nu, 0.0f);
    #pragma unroll
    for (int it = 0; it < 2; ++it)
        tl = fmaxf((xm * coshq(tl) - C) / nu, 0.0f);
    tl = fminf(tl, TMAX);

    const int plo = (int)(tl * INVH);
    const int phi = min(NQ - 1, (int)(th * INVH) + 1);

    const float4* tab;
    int q0, q1;
    if (xm >= 10.0f) {                  // coarse stride-4 rule is accurate enough
        tab = sC + NP;
        q0 = max(0, (plo >> 3) - 1);
        q1 = min(NP4, (phi >> 3) + 2);
    } else {                            // full resolution (robust small-x path)
        tab = sC;
        q0 = max(0, (plo >> 1) - 3);
        q1 = min(NP, (phi >> 1) + 4);
    }
    q0 = __builtin_amdgcn_readfirstlane(q0);
    q1 = __builtin_amdgcn_readfirstlane(q1);

    // ---- quadrature over the significant window only ----
    #pragma unroll 2
    for (int q = q0; q < q1; ++q) {
        const float4 cc = tab[q];
        acc[0] = fmaf(cc.y, __builtin_amdgcn_exp2f(xn[0] * cc.x), acc[0]);
        acc[1] = fmaf(cc.y, __builtin_amdgcn_exp2f(xn[1] * cc.x), acc[1]);
        acc[0] = fmaf(cc.w, __builtin_amdgcn_exp2f(xn[0] * cc.z), acc[0]);
        acc[1] = fmaf(cc.w, __builtin_amdgcn_exp2f(xn[1] * cc.z), acc[1]);
    }

    // ---- epilogue: val = norm * x^nu * acc ; diagonal = var ; mirror via LDS ----
    #pragma unroll
    for (int k = 0; k < 2; ++k) {
        const float pw = __builtin_amdgcn_exp2f(nu * __builtin_amdgcn_logf(x[k]));
        float val = norm * pw * acc[k];
        if (isdiag[k]) val = var;
        out[(i0 + i2 + k) * N + (j0 + jl)] = val;
        sT[i2 + k][jl] = val;
    }
    if (bx != by) {
        __syncthreads();
        #pragma unroll
        for (int k = 0; k < 2; ++k) {
            const int a = i2 + k;
            out[(j0 + a) * N + (i0 + jl)] = sT[jl][a];
        }
    }
}

extern "C" void kernel_launch(void* const* d_in, const int* in_sizes, int n_in,
                              void* d_out, int out_size, void* d_ws, size_t ws_size,
                              hipStream_t stream) {
    const float* X  = (const float*)d_in[0];
    const float* nu = (const float*)d_in[1];
    const float* lv = (const float*)d_in[2];
    const float* ll = (const float*)d_in[3];
    float* out = (float*)d_out;

    const int N  = in_sizes[0] / 32;              // 1024
    const int nt = N / 16;
    const int nblk = nt * (nt + 1) / 2;           // 2080
    matern_tri_kernel<<<nblk, 128, 0, stream>>>(X, nu, lv, ll, out, N);
}